// Round 1
// baseline (824.331 us; speedup 1.0000x reference)
//
#include <hip/hip_runtime.h>
#include <hip/hip_bf16.h>
#include <stdint.h>

#define N_TOK 4096
#define D_ 1024
#define H_ 4096
#define E_ 8
#define NSLOT (N_TOK*2)
#define BM 128
#define BN 128
#define BK 32
#define MAXT 72   // max M-tiles: 8192/128 + 8 experts ceil slack

typedef __attribute__((ext_vector_type(8))) short short8;
typedef __attribute__((ext_vector_type(4))) float floatx4;

__device__ __forceinline__ unsigned short f2bf(float f){
    union { float f; unsigned int u; } c; c.f = f;
    unsigned int u = c.u;
    unsigned int r = (u + 0x7fffu + ((u >> 16) & 1u)) >> 16;  // RNE
    return (unsigned short)r;
}

// ---------------- Router: fp32 logits, top-2, softmax(2), count per expert ---
__global__ __launch_bounds__(64) void router_kernel(
    const float* __restrict__ x, const float* __restrict__ Wr,
    const float* __restrict__ br, int* __restrict__ counts,
    int* __restrict__ topIdx, float* __restrict__ topGate)
{
    int n = blockIdx.x;
    int lane = threadIdx.x;
    const float4* xp = (const float4*)(x + (size_t)n * D_);
    float acc[E_];
#pragma unroll
    for (int e = 0; e < E_; e++) acc[e] = 0.f;
#pragma unroll
    for (int j = 0; j < 4; j++){
        int idx = j * 64 + lane;           // 256 float4 per row
        float4 xv = xp[idx];
#pragma unroll
        for (int e = 0; e < E_; e++){
            float4 wv = ((const float4*)(Wr + (size_t)e * D_))[idx];
            acc[e] += xv.x*wv.x + xv.y*wv.y + xv.z*wv.z + xv.w*wv.w;
        }
    }
#pragma unroll
    for (int e = 0; e < E_; e++){
        float v = acc[e];
        for (int off = 32; off > 0; off >>= 1) v += __shfl_xor(v, off, 64);
        acc[e] = v;
    }
    if (lane == 0){
        float best = -1e30f, second = -1e30f; int bi = 0, si = 0;
#pragma unroll
        for (int e = 0; e < E_; e++){
            float v = acc[e] + br[e];
            if (v > best){ second = best; si = bi; best = v; bi = e; }
            else if (v > second){ second = v; si = e; }
        }
        float e1 = __expf(second - best);
        float denom = 1.f + e1;
        topIdx[n*2+0] = bi;  topIdx[n*2+1] = si;
        topGate[n*2+0] = 1.f/denom;  topGate[n*2+1] = e1/denom;
        atomicAdd(&counts[bi], 1);
        atomicAdd(&counts[si], 1);
    }
}

// ---------------- Scan: offsets + tile->(expert,rowBase) map (device-side) ---
__global__ void scan_kernel(int* hdr){
    int* counts  = hdr;        // [0..7]
    int* offsets = hdr + 16;   // [16..24]
    int* tileE   = hdr + 32;   // [32..111]
    int* tileR   = hdr + 112;  // [112..191]
    offsets[0] = 0;
    for (int e = 0; e < E_; e++) offsets[e+1] = offsets[e] + counts[e];
    int t = 0;
    for (int e = 0; e < E_; e++){
        int c = counts[e];
        int nt = (c + BM - 1) / BM;
        for (int i = 0; i < nt; i++){ tileE[t] = e; tileR[t] = offsets[e] + i*BM; t++; }
    }
    for (; t < MAXT; t++){ tileE[t] = -1; tileR[t] = 0; }
}

// ---------------- Gather: assign compact row, copy x row -> bf16 -------------
__global__ __launch_bounds__(64) void gather_kernel(
    const float* __restrict__ x, const int* __restrict__ topIdx,
    const float* __restrict__ topGate, int* hdr,
    int* __restrict__ rowTok, float* __restrict__ rowGate,
    unsigned short* __restrict__ xg)
{
    int slot = blockIdx.x;
    int n = slot >> 1;
    __shared__ int spos;
    if (threadIdx.x == 0){
        int e = topIdx[slot];
        int* cursors = hdr + 8;
        int* offsets = hdr + 16;
        int pos = offsets[e] + atomicAdd(&cursors[e], 1);
        rowTok[pos] = n;
        rowGate[pos] = topGate[slot];
        spos = pos;
    }
    __syncthreads();
    int pos = spos;
    const float4* xp = (const float4*)(x + (size_t)n * D_);
    ushort4* op = (ushort4*)(xg + (size_t)pos * D_);
#pragma unroll
    for (int j = 0; j < 4; j++){
        int idx = j * 64 + threadIdx.x;
        float4 v = xp[idx];
        ushort4 o; o.x=f2bf(v.x); o.y=f2bf(v.y); o.z=f2bf(v.z); o.w=f2bf(v.w);
        op[idx] = o;
    }
}

// ---------------- Grouped GEMM (A bf16 K-major, W fp32 K-major) --------------
// MODE 1: h = relu(A@W^T + bias) -> bf16 hout[row*H_ + col]
// MODE 2: atomicAdd(out[tok*D_ + col], gate * (A@W^T + bias))
template<int MODE>
__global__ __launch_bounds__(256) void moe_gemm(
    const unsigned short* __restrict__ A, int Ktot,   // lda == ldb == Ktot
    const float* __restrict__ Wbase, size_t wStride,
    const float* __restrict__ biasBase, int biasStride,
    const int* __restrict__ hdr,
    const int* __restrict__ rowTok, const float* __restrict__ rowGate,
    unsigned short* __restrict__ hout, float* __restrict__ out)
{
    const int bx = blockIdx.x, by = blockIdx.y;
    const int* tileE   = hdr + 32;
    const int* tileR   = hdr + 112;
    const int* offsets = hdr + 16;
    int e = tileE[bx];
    if (e < 0) return;
    int rowBase = tileR[bx];
    int validRows = offsets[e+1] - rowBase;   // may exceed 128 (interior tiles)

    __shared__ __align__(16) unsigned short As[BM][40];  // +8 pad: bank spread
    __shared__ __align__(16) unsigned short Bs[BN][40];

    const float* Wexp  = Wbase + (size_t)e * wStride;
    const float* biasE = biasBase + (size_t)e * biasStride;

    const int tid  = threadIdx.x;
    const int lane = tid & 63, wave = tid >> 6;
    const int wm = wave & 1, wn = wave >> 1;
    const int l16 = lane & 15, quad = lane >> 4;

    floatx4 acc[4][4];
#pragma unroll
    for (int mi = 0; mi < 4; mi++)
#pragma unroll
        for (int ni = 0; ni < 4; ni++)
            acc[mi][ni] = (floatx4){0.f,0.f,0.f,0.f};

    for (int k0 = 0; k0 < Ktot; k0 += BK){
        // stage A: 128x32 bf16 = 512 segs of 16B, 2 per thread
        int4 aReg[2];
#pragma unroll
        for (int i = 0; i < 2; i++){
            int s = i*256 + tid;
            int r = s >> 2, seg = s & 3;
            int4 v; v.x = v.y = v.z = v.w = 0;
            if (r < validRows)
                v = *(const int4*)(A + (size_t)(rowBase + r) * Ktot + k0 + seg*8);
            aReg[i] = v;
        }
        // stage B: 128x32 fp32 = 1024 segs of 16B, 4 per thread
        float4 bReg[4];
#pragma unroll
        for (int i = 0; i < 4; i++){
            int s = i*256 + tid;
            int r = s >> 3, seg = s & 7;
            bReg[i] = *(const float4*)(Wexp + (size_t)(by*BN + r) * Ktot + k0 + seg*4);
        }
        __syncthreads();
#pragma unroll
        for (int i = 0; i < 2; i++){
            int s = i*256 + tid; int r = s >> 2, seg = s & 3;
            *(int4*)&As[r][seg*8] = aReg[i];
        }
#pragma unroll
        for (int i = 0; i < 4; i++){
            int s = i*256 + tid; int r = s >> 3, seg = s & 7;
            ushort4 o; o.x=f2bf(bReg[i].x); o.y=f2bf(bReg[i].y);
            o.z=f2bf(bReg[i].z); o.w=f2bf(bReg[i].w);
            *(ushort4*)&Bs[r][seg*4] = o;
        }
        __syncthreads();

        short8 af[4], bf[4];
#pragma unroll
        for (int mi = 0; mi < 4; mi++)
            af[mi] = *(const short8*)&As[wm*64 + mi*16 + l16][quad*8];
#pragma unroll
        for (int ni = 0; ni < 4; ni++)
            bf[ni] = *(const short8*)&Bs[wn*64 + ni*16 + l16][quad*8];
#pragma unroll
        for (int mi = 0; mi < 4; mi++)
#pragma unroll
            for (int ni = 0; ni < 4; ni++)
                acc[mi][ni] = __builtin_amdgcn_mfma_f32_16x16x32_bf16(
                    af[mi], bf[ni], acc[mi][ni], 0, 0, 0);
    }

    // epilogue: D element (m = quad*4 + r, n = l16) per 16x16 tile
#pragma unroll
    for (int mi = 0; mi < 4; mi++){
#pragma unroll
        for (int r = 0; r < 4; r++){
            int rl = wm*64 + mi*16 + quad*4 + r;
            if (rl >= validRows) continue;
            int grow = rowBase + rl;
            int   tok  = 0;
            float gate = 0.f;
            if (MODE == 2){ tok = rowTok[grow]; gate = rowGate[grow]; }
#pragma unroll
            for (int ni = 0; ni < 4; ni++){
                int gcol = by*BN + wn*64 + ni*16 + l16;
                float v = acc[mi][ni][r] + biasE[gcol];
                if (MODE == 1){
                    v = v > 0.f ? v : 0.f;
                    hout[(size_t)grow * H_ + gcol] = f2bf(v);
                } else {
                    atomicAdd(out + (size_t)tok * D_ + gcol, gate * v);
                }
            }
        }
    }
}

// ---------------- launch -----------------------------------------------------
extern "C" void kernel_launch(void* const* d_in, const int* in_sizes, int n_in,
                              void* d_out, int out_size, void* d_ws, size_t ws_size,
                              hipStream_t stream)
{
    (void)in_sizes; (void)n_in; (void)ws_size;
    const float* x  = (const float*)d_in[0];
    const float* Wr = (const float*)d_in[1];
    const float* br = (const float*)d_in[2];
    const float* W1 = (const float*)d_in[3];
    const float* b1 = (const float*)d_in[4];
    const float* W2 = (const float*)d_in[5];
    const float* b2 = (const float*)d_in[6];
    float* out = (float*)d_out;

    char* ws = (char*)d_ws;
    int*   hdr     = (int*)ws;                      // counts/cursors/offsets/tiles (4 KB zeroed)
    int*   topIdx  = (int*)  (ws + 4096);
    float* topGate = (float*)(ws + 36864);
    int*   rowTok  = (int*)  (ws + 69632);
    float* rowGate = (float*)(ws + 102400);
    unsigned short* xg   = (unsigned short*)(ws + 262144);    // 8192x1024 bf16 (16.8 MB)
    unsigned short* hbuf = (unsigned short*)(ws + 17825792);  // 8192x4096 bf16 (67 MB)

    hipMemsetAsync(hdr, 0, 4096, stream);
    hipMemsetAsync(d_out, 0, (size_t)out_size * sizeof(float), stream);

    router_kernel<<<N_TOK, 64, 0, stream>>>(x, Wr, br, hdr, topIdx, topGate);
    scan_kernel<<<1, 1, 0, stream>>>(hdr);
    gather_kernel<<<NSLOT, 64, 0, stream>>>(x, topIdx, topGate, hdr, rowTok, rowGate, xg);
    moe_gemm<1><<<dim3(MAXT, H_/BN), 256, 0, stream>>>(
        xg, D_, W1, (size_t)H_ * D_, b1, H_, hdr, rowTok, rowGate, hbuf, nullptr);
    moe_gemm<2><<<dim3(MAXT, D_/BN), 256, 0, stream>>>(
        hbuf, H_, W2, (size_t)D_ * H_, b2, D_, hdr, rowTok, rowGate, nullptr, out);
}

// Round 2
// 648.967 us; speedup vs baseline: 1.2702x; 1.2702x over previous
//
#include <hip/hip_runtime.h>
#include <hip/hip_bf16.h>
#include <stdint.h>

#define N_TOK 4096
#define D_ 1024
#define H_ 4096
#define E_ 8
#define NSLOT (N_TOK*2)
#define BM 128
#define BN 128
#define BK 32
#define MAXT 72

typedef __attribute__((ext_vector_type(8))) short short8;
typedef __attribute__((ext_vector_type(4))) float floatx4;
typedef unsigned int u32;

__device__ __forceinline__ unsigned short f2bf(float f){
    union { float f; unsigned int u; } c; c.f = f;
    unsigned int u = c.u;
    unsigned int r = (u + 0x7fffu + ((u >> 16) & 1u)) >> 16;  // RNE
    return (unsigned short)r;
}

__device__ __forceinline__ void async16(const void* g, void* l){
    __builtin_amdgcn_global_load_lds(
        (const __attribute__((address_space(1))) u32*)g,
        (__attribute__((address_space(3))) u32*)l, 16, 0, 0);
}

// hdr int layout: [16..24] offsets, [32..103] tileE, [112..183] tileR,
//                 [256..511] blockCnt[32][8], [512..767] blockOff[32][8]

// ---------------- Router: fp32 logits, top-2, softmax(2). No atomics. --------
__global__ __launch_bounds__(256) void router_kernel(
    const float* __restrict__ x, const float* __restrict__ Wr,
    const float* __restrict__ br, int* __restrict__ topIdx,
    float* __restrict__ topGate)
{
    int n = blockIdx.x * 4 + (threadIdx.x >> 6);
    int lane = threadIdx.x & 63;
    const float4* xp = (const float4*)(x + (size_t)n * D_);
    float acc[E_];
#pragma unroll
    for (int e = 0; e < E_; e++) acc[e] = 0.f;
#pragma unroll
    for (int j = 0; j < 4; j++){
        int idx = j * 64 + lane;
        float4 xv = xp[idx];
#pragma unroll
        for (int e = 0; e < E_; e++){
            float4 wv = ((const float4*)(Wr + (size_t)e * D_))[idx];
            acc[e] += xv.x*wv.x + xv.y*wv.y + xv.z*wv.z + xv.w*wv.w;
        }
    }
#pragma unroll
    for (int e = 0; e < E_; e++){
        float v = acc[e];
        for (int off = 32; off > 0; off >>= 1) v += __shfl_xor(v, off, 64);
        acc[e] = v;
    }
    if (lane == 0){
        float best = -1e30f, second = -1e30f; int bi = 0, si = 0;
#pragma unroll
        for (int e = 0; e < E_; e++){
            float v = acc[e] + br[e];
            if (v > best){ second = best; si = bi; best = v; bi = e; }
            else if (v > second){ second = v; si = e; }
        }
        float e1 = __expf(second - best);
        float denom = 1.f + e1;
        topIdx[n*2+0] = bi;  topIdx[n*2+1] = si;
        topGate[n*2+0] = 1.f/denom;  topGate[n*2+1] = e1/denom;
    }
}

// ---------------- Per-chunk histogram (counting sort pass 1) -----------------
__global__ __launch_bounds__(256) void hist_kernel(
    const int* __restrict__ topIdx, int* __restrict__ hdr)
{
    __shared__ int c[E_];
    int t = threadIdx.x;
    if (t < E_) c[t] = 0;
    __syncthreads();
    int e = topIdx[blockIdx.x * 256 + t];
    atomicAdd(&c[e], 1);
    __syncthreads();
    if (t < E_) hdr[256 + blockIdx.x * E_ + t] = c[t];
}

// ---------------- Scan: offsets, per-chunk bases, tile map -------------------
__global__ __launch_bounds__(64) void scan2_kernel(int* __restrict__ hdr)
{
    __shared__ int cnt[32 * E_];
    __shared__ int tot[E_];
    __shared__ int offs[E_ + 1];
    int t = threadIdx.x;
    for (int i = t; i < 32 * E_; i += 64) cnt[i] = hdr[256 + i];
    __syncthreads();
    if (t < E_){
        int s = 0;
        for (int b = 0; b < 32; b++) s += cnt[b * E_ + t];
        tot[t] = s;
    }
    __syncthreads();
    if (t == 0){
        int o = 0;
        for (int e = 0; e < E_; e++){ offs[e] = o; o += tot[e]; }
        offs[E_] = o;
    }
    __syncthreads();
    if (t < E_ + 1) hdr[16 + t] = offs[t];
    if (t < E_){
        int run = offs[t];
        for (int b = 0; b < 32; b++){ hdr[512 + b * E_ + t] = run; run += cnt[b * E_ + t]; }
    }
    if (t == 0){
        int tn = 0;
        for (int e = 0; e < E_; e++){
            int nt = (tot[e] + BM - 1) >> 7;
            for (int i = 0; i < nt; i++){ hdr[32 + tn] = e; hdr[112 + tn] = offs[e] + (i << 7); tn++; }
        }
        for (; tn < MAXT; tn++){ hdr[32 + tn] = -1; hdr[112 + tn] = 0; }
    }
}

// ---------------- Rank within chunk -> compact position ---------------------
__global__ __launch_bounds__(256) void pos_kernel(
    const int* __restrict__ topIdx, const float* __restrict__ topGate,
    const int* __restrict__ hdr, int* __restrict__ posOf,
    int* __restrict__ rowTok, float* __restrict__ rowGate)
{
    __shared__ int c[E_];
    int t = threadIdx.x;
    if (t < E_) c[t] = 0;
    __syncthreads();
    int slot = blockIdx.x * 256 + t;
    int e = topIdx[slot];
    int r = atomicAdd(&c[e], 1);
    int pos = hdr[512 + blockIdx.x * E_ + e] + r;
    posOf[slot] = pos;
    rowTok[pos] = slot >> 1;
    rowGate[pos] = topGate[slot];
}

// ---------------- Gather copy: x row -> bf16 compact row ---------------------
__global__ __launch_bounds__(256) void copy_kernel(
    const float* __restrict__ x, const int* __restrict__ posOf,
    unsigned short* __restrict__ xg)
{
    int slot = blockIdx.x * 4 + (threadIdx.x >> 6);
    int lane = threadIdx.x & 63;
    int n = slot >> 1;
    int pos = posOf[slot];
    const float4* xp = (const float4*)(x + (size_t)n * D_);
    ushort4* op = (ushort4*)(xg + (size_t)pos * D_);
#pragma unroll
    for (int j = 0; j < 4; j++){
        float4 v = xp[j * 64 + lane];
        ushort4 o; o.x=f2bf(v.x); o.y=f2bf(v.y); o.z=f2bf(v.z); o.w=f2bf(v.w);
        op[j * 64 + lane] = o;
    }
}

// ---------------- Grouped GEMM, m97-style async staging ----------------------
// A: bf16 [rows][Ktot] compact. B: fp32 weights [E][N][Ktot].
// MODE 1: hout = relu(A@W^T+b) bf16.  MODE 2: out[tok] += gate*(A@W^T+b).
template<int MODE>
__global__ __launch_bounds__(256) void moe_gemm(
    const unsigned short* __restrict__ A, int Ktot,
    const float* __restrict__ Wbase, size_t wStride,
    const float* __restrict__ biasBase, int biasStride,
    const int* __restrict__ hdr,
    const int* __restrict__ rowTok, const float* __restrict__ rowGate,
    unsigned short* __restrict__ hout, float* __restrict__ out)
{
    const int bx = blockIdx.x, by = blockIdx.y;
    int e = hdr[32 + bx];
    if (e < 0) return;
    int rowBase = hdr[112 + bx];
    int validRows = hdr[16 + e + 1] - rowBase;

    __shared__ __align__(16) unsigned short As[BM * BK];  // 8 KB, row stride 64B
    __shared__ __align__(16) float Bs[BN * BK];           // 16 KB, row stride 128B, XOR-swizzled granules

    const float* Wexp  = Wbase + (size_t)e * wStride + (size_t)(by * BN) * Ktot;
    const float* biasE = biasBase + (size_t)e * biasStride + by * BN;

    const int tid  = threadIdx.x;
    const int lane = tid & 63, wave = tid >> 6;
    const int wm = wave & 1, wn = wave >> 1;
    const int l16 = lane & 15, quad = lane >> 4;

    floatx4 acc[4][4];
#pragma unroll
    for (int mi = 0; mi < 4; mi++)
#pragma unroll
        for (int ni = 0; ni < 4; ni++)
            acc[mi][ni] = (floatx4){0.f,0.f,0.f,0.f};

    // precompute per-thread staging descriptors
    int aS[2], aRow[2], aCol[2];
#pragma unroll
    for (int i = 0; i < 2; i++){
        int s = wave * 128 + i * 64 + lane;      // 16B granule in As
        aS[i] = s;
        int r = rowBase + (s >> 2);
        aRow[i] = r < (NSLOT - 1) ? r : (NSLOT - 1);   // clamp: junk rows masked in epilogue
        aCol[i] = (s & 3) * 8;
    }
    int bS[4], bRow[4], bCol[4];
#pragma unroll
    for (int i = 0; i < 4; i++){
        int s = wave * 256 + i * 64 + lane;      // 16B granule in Bs
        bS[i] = s;
        int r = s >> 3, c = s & 7;
        bRow[i] = r;
        bCol[i] = (c ^ (r & 7)) * 4;             // XOR swizzle (bank-conflict-free frag reads)
    }

    for (int k0 = 0; k0 < Ktot; k0 += BK){
#pragma unroll
        for (int i = 0; i < 2; i++)
            async16(A + (size_t)aRow[i] * Ktot + k0 + aCol[i], (char*)As + aS[i] * 16);
#pragma unroll
        for (int i = 0; i < 4; i++)
            async16(Wexp + (size_t)bRow[i] * Ktot + k0 + bCol[i], (char*)Bs + bS[i] * 16);
        __syncthreads();

        short8 af[4];
#pragma unroll
        for (int mi = 0; mi < 4; mi++){
            int r = wm * 64 + mi * 16 + l16;
            af[mi] = *(const short8*)(As + r * BK + quad * 8);
        }
        short8 bfr[4];
#pragma unroll
        for (int ni = 0; ni < 4; ni++){
            int n = wn * 64 + ni * 16 + l16;
            int g0 = (2 * quad)     ^ (n & 7);
            int g1 = (2 * quad + 1) ^ (n & 7);
            float4 u0 = *(const float4*)(Bs + n * BK + g0 * 4);
            float4 u1 = *(const float4*)(Bs + n * BK + g1 * 4);
            union { short8 s; __hip_bfloat162 h[4]; } u;
            u.h[0] = __float22bfloat162_rn(make_float2(u0.x, u0.y));
            u.h[1] = __float22bfloat162_rn(make_float2(u0.z, u0.w));
            u.h[2] = __float22bfloat162_rn(make_float2(u1.x, u1.y));
            u.h[3] = __float22bfloat162_rn(make_float2(u1.z, u1.w));
            bfr[ni] = u.s;
        }
#pragma unroll
        for (int mi = 0; mi < 4; mi++)
#pragma unroll
            for (int ni = 0; ni < 4; ni++)
                acc[mi][ni] = __builtin_amdgcn_mfma_f32_16x16x32_bf16(
                    af[mi], bfr[ni], acc[mi][ni], 0, 0, 0);
        __syncthreads();
    }

#pragma unroll
    for (int mi = 0; mi < 4; mi++){
#pragma unroll
        for (int r = 0; r < 4; r++){
            int rl = wm * 64 + mi * 16 + quad * 4 + r;
            if (rl >= validRows) continue;
            int grow = rowBase + rl;
            int   tok  = 0;
            float gate = 0.f;
            if (MODE == 2){ tok = rowTok[grow]; gate = rowGate[grow]; }
#pragma unroll
            for (int ni = 0; ni < 4; ni++){
                int gcol = by * BN + wn * 64 + ni * 16 + l16;
                float v = acc[mi][ni][r] + biasE[wn * 64 + ni * 16 + l16];
                if (MODE == 1){
                    v = v > 0.f ? v : 0.f;
                    hout[(size_t)grow * H_ + gcol] = f2bf(v);
                } else {
                    atomicAdd(out + (size_t)tok * D_ + gcol, gate * v);
                }
            }
        }
    }
}

// ---------------- launch -----------------------------------------------------
extern "C" void kernel_launch(void* const* d_in, const int* in_sizes, int n_in,
                              void* d_out, int out_size, void* d_ws, size_t ws_size,
                              hipStream_t stream)
{
    (void)in_sizes; (void)n_in; (void)ws_size;
    const float* x  = (const float*)d_in[0];
    const float* Wr = (const float*)d_in[1];
    const float* br = (const float*)d_in[2];
    const float* W1 = (const float*)d_in[3];
    const float* b1 = (const float*)d_in[4];
    const float* W2 = (const float*)d_in[5];
    const float* b2 = (const float*)d_in[6];
    float* out = (float*)d_out;

    char* ws = (char*)d_ws;
    int*   hdr     = (int*)ws;                       // 4 KB, every used field written on-device
    int*   topIdx  = (int*)  (ws + 4096);
    float* topGate = (float*)(ws + 36864);
    int*   posOf   = (int*)  (ws + 69632);
    int*   rowTok  = (int*)  (ws + 102400);
    float* rowGate = (float*)(ws + 135168);
    unsigned short* xg   = (unsigned short*)(ws + 262144);    // 8192x1024 bf16
    unsigned short* hbuf = (unsigned short*)(ws + 17039360);  // 8192x4096 bf16 (ends 84.1 MB)

    hipMemsetAsync(d_out, 0, (size_t)out_size * sizeof(float), stream);

    router_kernel<<<N_TOK/4, 256, 0, stream>>>(x, Wr, br, topIdx, topGate);
    hist_kernel<<<32, 256, 0, stream>>>(topIdx, hdr);
    scan2_kernel<<<1, 64, 0, stream>>>(hdr);
    pos_kernel<<<32, 256, 0, stream>>>(topIdx, topGate, hdr, posOf, rowTok, rowGate);
    copy_kernel<<<NSLOT/4, 256, 0, stream>>>(x, posOf, xg);
    moe_gemm<1><<<dim3(MAXT, H_/BN), 256, 0, stream>>>(
        xg, D_, W1, (size_t)H_ * D_, b1, H_, hdr, rowTok, rowGate, hbuf, nullptr);
    moe_gemm<2><<<dim3(MAXT, D_/BN), 256, 0, stream>>>(
        hbuf, H_, W2, (size_t)D_ * H_, b2, D_, hdr, rowTok, rowGate, nullptr, out);
}